// Round 1
// baseline (370.754 us; speedup 1.0000x reference)
//
#include <hip/hip_runtime.h>

#define NRAYS 262144
#define KF 4
#define DF 24

__device__ __forceinline__ float4 wsum3(float w0, const float4& a0,
                                        float w1, const float4& a1,
                                        float w2, const float4& a2) {
    float4 o;
    o.x = w0 * a0.x + w1 * a1.x + w2 * a2.x;
    o.y = w0 * a0.y + w1 * a1.y + w2 * a2.y;
    o.z = w0 * a0.z + w1 * a1.z + w2 * a2.z;
    o.w = w0 * a0.w + w1 * a1.w + w2 * a2.w;
    return o;
}

__global__ __launch_bounds__(256) void dnmp_interp_sort(
    const float* __restrict__ bary_coords,  // [P,4,3]
    const float* __restrict__ zbuf,         // [P,4]
    const float* __restrict__ verts,        // [V,3]
    const float* __restrict__ vfeat,        // [V,24]
    const float* __restrict__ vnorm,        // [V,3]
    const int*   __restrict__ p2f_all,      // [P,4]
    const int*   __restrict__ faces,        // [F,3]
    const int*   __restrict__ pix,          // [R]
    float* __restrict__ out_tex,            // [R,4,24]
    float* __restrict__ out_pts,            // [R,4,3]
    float* __restrict__ out_dep,            // [R,4]
    float* __restrict__ out_nrm)            // [R,4,3]
{
    int r = blockIdx.x * blockDim.x + threadIdx.x;
    if (r >= NRAYS) return;
    int p = pix[r];

    // pixel-row loads (all rows 16B-aligned)
    int4   pf = *reinterpret_cast<const int4*>(p2f_all + (size_t)p * 4);
    float4 dz = *reinterpret_cast<const float4*>(zbuf + (size_t)p * 4);
    float4 b0 = *reinterpret_cast<const float4*>(bary_coords + (size_t)p * 12);
    float4 b1 = *reinterpret_cast<const float4*>(bary_coords + (size_t)p * 12 + 4);
    float4 b2 = *reinterpret_cast<const float4*>(bary_coords + (size_t)p * 12 + 8);

    int   f[KF]       = { pf.x, pf.y, pf.z, pf.w };
    float d[KF]       = { dz.x, dz.y, dz.z, dz.w };
    float bw[KF][3]   = { { b0.x, b0.y, b0.z },
                          { b0.w, b1.x, b1.y },
                          { b1.z, b1.w, b2.x },
                          { b2.y, b2.z, b2.w } };

    // fallback: invalid (== -1) entries take k=0's face/bary/depth
    int   f0  = f[0];
    float d0  = d[0];
    float w00 = bw[0][0], w01 = bw[0][1], w02 = bw[0][2];
#pragma unroll
    for (int k = 1; k < KF; ++k) {
        if (f[k] == -1) {
            f[k] = f0;
            d[k] = d0;
            bw[k][0] = w00; bw[k][1] = w01; bw[k][2] = w02;
        }
    }

    // stable argsort rank over the (fallback-applied) depths
    int rank[KF];
#pragma unroll
    for (int k = 0; k < KF; ++k) {
        int rk = 0;
#pragma unroll
        for (int j = 0; j < KF; ++j) {
            bool lt = (d[j] < d[k]) || (d[j] == d[k] && j < k);
            rk += lt ? 1 : 0;
        }
        rank[k] = rk;
    }

#pragma unroll
    for (int k = 0; k < KF; ++k) {
        int  fk   = f[k];
        bool mask = fk < 0;
        int  idx  = mask ? 0 : fk;

        int i0 = faces[(size_t)idx * 3 + 0];
        int i1 = faces[(size_t)idx * 3 + 1];
        int i2 = faces[(size_t)idx * 3 + 2];

        float w0 = mask ? 0.f : bw[k][0];
        float w1 = mask ? 0.f : bw[k][1];
        float w2 = mask ? 0.f : bw[k][2];

        int slot = rank[k];
        int base = r * KF + slot;

        // texture features: 24 floats = 6 aligned float4 per vertex row
        const float4* t0 = reinterpret_cast<const float4*>(vfeat + (size_t)i0 * DF);
        const float4* t1 = reinterpret_cast<const float4*>(vfeat + (size_t)i1 * DF);
        const float4* t2 = reinterpret_cast<const float4*>(vfeat + (size_t)i2 * DF);
        float4* otex = reinterpret_cast<float4*>(out_tex) + (size_t)base * 6;
#pragma unroll
        for (int t = 0; t < 6; ++t) {
            otex[t] = wsum3(w0, t0[t], w1, t1[t], w2, t2[t]);
        }

        // points (3 floats/vertex)
        const float* v0 = verts + (size_t)i0 * 3;
        const float* v1 = verts + (size_t)i1 * 3;
        const float* v2 = verts + (size_t)i2 * 3;
#pragma unroll
        for (int j = 0; j < 3; ++j) {
            out_pts[(size_t)base * 3 + j] = w0 * v0[j] + w1 * v1[j] + w2 * v2[j];
        }

        // normals (3 floats/vertex)
        const float* n0 = vnorm + (size_t)i0 * 3;
        const float* n1 = vnorm + (size_t)i1 * 3;
        const float* n2 = vnorm + (size_t)i2 * 3;
#pragma unroll
        for (int j = 0; j < 3; ++j) {
            out_nrm[(size_t)base * 3 + j] = w0 * n0[j] + w1 * n1[j] + w2 * n2[j];
        }

        out_dep[base] = d[k];
    }
}

extern "C" void kernel_launch(void* const* d_in, const int* in_sizes, int n_in,
                              void* d_out, int out_size, void* d_ws, size_t ws_size,
                              hipStream_t stream) {
    const float* bary_coords = (const float*)d_in[0];  // [P,4,3]
    const float* zbuf        = (const float*)d_in[1];  // [P,4]
    const float* verts       = (const float*)d_in[2];  // [V,3]
    const float* vfeat       = (const float*)d_in[3];  // [V,24]
    const float* vnorm       = (const float*)d_in[4];  // [V,3]
    const int*   p2f         = (const int*)d_in[5];    // [P,4]
    const int*   faces       = (const int*)d_in[6];    // [F,3]
    const int*   pix         = (const int*)d_in[7];    // [R]

    float* out     = (float*)d_out;
    float* out_tex = out;                                   // R*4*24
    float* out_pts = out_tex + (size_t)NRAYS * KF * DF;     // R*4*3
    float* out_dep = out_pts + (size_t)NRAYS * KF * 3;      // R*4
    float* out_nrm = out_dep + (size_t)NRAYS * KF;          // R*4*3

    dim3 block(256);
    dim3 grid((NRAYS + 255) / 256);
    dnmp_interp_sort<<<grid, block, 0, stream>>>(
        bary_coords, zbuf, verts, vfeat, vnorm, p2f, faces, pix,
        out_tex, out_pts, out_dep, out_nrm);
}

// Round 2
// 197.644 us; speedup vs baseline: 1.8759x; 1.8759x over previous
//
#include <hip/hip_runtime.h>

#define NRAYS 262144
#define KF 4
#define DF 24
#define NVERT 420000

// packed vertex record: 32 floats = 128B
// float4[0..5] = feat[0..23], float4[6] = {px,py,pz,nx}, float4[7] = {ny,nz,0,0}

__global__ __launch_bounds__(256) void pack_verts(
    const float* __restrict__ verts,   // [V,3]
    const float* __restrict__ vfeat,   // [V,24]
    const float* __restrict__ vnorm,   // [V,3]
    float4* __restrict__ pk)           // [V*8]
{
    int tid = blockIdx.x * blockDim.x + threadIdx.x;
    if (tid >= NVERT * 8) return;
    int v = tid >> 3, q = tid & 7;
    float4 o;
    if (q < 6) {
        o = *reinterpret_cast<const float4*>(vfeat + (size_t)v * DF + q * 4);
    } else if (q == 6) {
        o.x = verts[(size_t)v * 3 + 0];
        o.y = verts[(size_t)v * 3 + 1];
        o.z = verts[(size_t)v * 3 + 2];
        o.w = vnorm[(size_t)v * 3 + 0];
    } else {
        o.x = vnorm[(size_t)v * 3 + 1];
        o.y = vnorm[(size_t)v * 3 + 2];
        o.z = 0.f; o.w = 0.f;
    }
    pk[tid] = o;
}

template<bool PACKED>
__global__ __launch_bounds__(256) void dnmp_rk(
    const float* __restrict__ bary_coords,  // [P,4,3]
    const float* __restrict__ zbuf,         // [P,4]
    const float* __restrict__ verts,        // [V,3]
    const float* __restrict__ vfeat,        // [V,24]
    const float* __restrict__ vnorm,        // [V,3]
    const int*   __restrict__ p2f_all,      // [P,4]
    const int*   __restrict__ faces,        // [F,3]
    const int*   __restrict__ pix,          // [R]
    const float4* __restrict__ pk,          // [V*8] packed (or null)
    float* __restrict__ out_tex,            // [R,4,24]
    float* __restrict__ out_pts,            // [R,4,3]
    float* __restrict__ out_dep,            // [R,4]
    float* __restrict__ out_nrm)            // [R,4,3]
{
    int tid = blockIdx.x * blockDim.x + threadIdx.x;
    int r = tid >> 2;
    if (r >= NRAYS) return;
    int k = tid & 3;
    int lane = threadIdx.x & 63;
    int gbase = lane & ~3;   // base lane of this ray's 4-lane group

    int p = pix[r];
    int   f = p2f_all[(size_t)p * 4 + k];
    float d = zbuf[(size_t)p * 4 + k];
    const float* bb = bary_coords + (size_t)p * 12 + k * 3;
    float w0 = bb[0], w1 = bb[1], w2 = bb[2];

    // fallback: invalid (== -1) entries take k=0's face/bary/depth
    int   f0  = __shfl(f,  gbase, 64);
    float dd0 = __shfl(d,  gbase, 64);
    float w00 = __shfl(w0, gbase, 64);
    float w01 = __shfl(w1, gbase, 64);
    float w02 = __shfl(w2, gbase, 64);
    if (f == -1) { f = f0; d = dd0; w0 = w00; w1 = w01; w2 = w02; }

    // stable argsort rank over post-fallback depths (cross-lane within group)
    int rank = 0;
#pragma unroll
    for (int j = 0; j < 4; ++j) {
        float dj = __shfl(d, gbase + j, 64);
        rank += (dj < d || (dj == d && j < k)) ? 1 : 0;
    }

    bool mask = f < 0;
    int  idx  = mask ? 0 : f;
    if (mask) { w0 = 0.f; w1 = 0.f; w2 = 0.f; }

    int i0 = faces[(size_t)idx * 3 + 0];
    int i1 = faces[(size_t)idx * 3 + 1];
    int i2 = faces[(size_t)idx * 3 + 2];

    float acc[30];
#pragma unroll
    for (int i = 0; i < 30; ++i) acc[i] = 0.f;

    const int   vi[3] = { i0, i1, i2 };
    const float ww[3] = { w0, w1, w2 };

#pragma unroll
    for (int t = 0; t < 3; ++t) {
        float w = ww[t];
        if (PACKED) {
            const float4* row = pk + (size_t)vi[t] * 8;
#pragma unroll
            for (int q = 0; q < 6; ++q) {
                float4 a = row[q];
                acc[q * 4 + 0] += w * a.x;
                acc[q * 4 + 1] += w * a.y;
                acc[q * 4 + 2] += w * a.z;
                acc[q * 4 + 3] += w * a.w;
            }
            float4 a6 = row[6];
            float4 a7 = row[7];
            acc[24] += w * a6.x; acc[25] += w * a6.y; acc[26] += w * a6.z;
            acc[27] += w * a6.w; acc[28] += w * a7.x; acc[29] += w * a7.y;
        } else {
            const float4* trow = reinterpret_cast<const float4*>(vfeat + (size_t)vi[t] * DF);
#pragma unroll
            for (int q = 0; q < 6; ++q) {
                float4 a = trow[q];
                acc[q * 4 + 0] += w * a.x;
                acc[q * 4 + 1] += w * a.y;
                acc[q * 4 + 2] += w * a.z;
                acc[q * 4 + 3] += w * a.w;
            }
            const float* vv = verts + (size_t)vi[t] * 3;
            const float* nn = vnorm + (size_t)vi[t] * 3;
            acc[24] += w * vv[0]; acc[25] += w * vv[1]; acc[26] += w * vv[2];
            acc[27] += w * nn[0]; acc[28] += w * nn[1]; acc[29] += w * nn[2];
        }
    }

    int ob = r * KF + rank;
    float4* ot = reinterpret_cast<float4*>(out_tex) + (size_t)ob * 6;
#pragma unroll
    for (int q = 0; q < 6; ++q) {
        ot[q] = make_float4(acc[q * 4 + 0], acc[q * 4 + 1], acc[q * 4 + 2], acc[q * 4 + 3]);
    }
    out_pts[(size_t)ob * 3 + 0] = acc[24];
    out_pts[(size_t)ob * 3 + 1] = acc[25];
    out_pts[(size_t)ob * 3 + 2] = acc[26];
    out_nrm[(size_t)ob * 3 + 0] = acc[27];
    out_nrm[(size_t)ob * 3 + 1] = acc[28];
    out_nrm[(size_t)ob * 3 + 2] = acc[29];
    out_dep[ob] = d;
}

extern "C" void kernel_launch(void* const* d_in, const int* in_sizes, int n_in,
                              void* d_out, int out_size, void* d_ws, size_t ws_size,
                              hipStream_t stream) {
    const float* bary_coords = (const float*)d_in[0];  // [P,4,3]
    const float* zbuf        = (const float*)d_in[1];  // [P,4]
    const float* verts       = (const float*)d_in[2];  // [V,3]
    const float* vfeat       = (const float*)d_in[3];  // [V,24]
    const float* vnorm       = (const float*)d_in[4];  // [V,3]
    const int*   p2f         = (const int*)d_in[5];    // [P,4]
    const int*   faces       = (const int*)d_in[6];    // [F,3]
    const int*   pix         = (const int*)d_in[7];    // [R]

    float* out     = (float*)d_out;
    float* out_tex = out;                                   // R*4*24
    float* out_pts = out_tex + (size_t)NRAYS * KF * DF;     // R*4*3
    float* out_dep = out_pts + (size_t)NRAYS * KF * 3;      // R*4
    float* out_nrm = out_dep + (size_t)NRAYS * KF;          // R*4*3

    const size_t pk_bytes = (size_t)NVERT * 8 * sizeof(float4);  // 53.76 MB

    dim3 block(256);
    dim3 grid_main(((size_t)NRAYS * KF + 255) / 256);

    if (ws_size >= pk_bytes) {
        float4* pk = (float4*)d_ws;
        dim3 grid_pack(((size_t)NVERT * 8 + 255) / 256);
        pack_verts<<<grid_pack, block, 0, stream>>>(verts, vfeat, vnorm, pk);
        dnmp_rk<true><<<grid_main, block, 0, stream>>>(
            bary_coords, zbuf, verts, vfeat, vnorm, p2f, faces, pix, pk,
            out_tex, out_pts, out_dep, out_nrm);
    } else {
        dnmp_rk<false><<<grid_main, block, 0, stream>>>(
            bary_coords, zbuf, verts, vfeat, vnorm, p2f, faces, pix, nullptr,
            out_tex, out_pts, out_dep, out_nrm);
    }
}

// Round 3
// 134.614 us; speedup vs baseline: 2.7542x; 1.4682x over previous
//
#include <hip/hip_runtime.h>

#define NRAYS 262144
#define KF 4
#define DF 24
#define NVERT 420000

// packed bf16 vertex record: 30 bf16 values + 2 pad = 64B = one cache line
// u16[0..23] = feat, u16[24..26] = pos, u16[27..29] = nrm

__device__ __forceinline__ unsigned int f2bf(float f) {
    union { float f; unsigned int i; } c; c.f = f;
    unsigned int i = c.i;
    return (i + 0x7fffu + ((i >> 16) & 1u)) >> 16;   // round-to-nearest-even
}

__device__ __forceinline__ float bf2f(unsigned int u16) {
    union { unsigned int i; float f; } c; c.i = u16 << 16; return c.f;
}

__global__ __launch_bounds__(256) void pack_verts_bf16(
    const float* __restrict__ verts,   // [V,3]
    const float* __restrict__ vfeat,   // [V,24]
    const float* __restrict__ vnorm,   // [V,3]
    uint4* __restrict__ pk)            // [V*4] (64B per vertex)
{
    int v = blockIdx.x * blockDim.x + threadIdx.x;
    if (v >= NVERT) return;

    float vals[30];
    const float4* fr = reinterpret_cast<const float4*>(vfeat + (size_t)v * DF);
#pragma unroll
    for (int q = 0; q < 6; ++q) {
        float4 a = fr[q];
        vals[q * 4 + 0] = a.x; vals[q * 4 + 1] = a.y;
        vals[q * 4 + 2] = a.z; vals[q * 4 + 3] = a.w;
    }
    vals[24] = verts[(size_t)v * 3 + 0];
    vals[25] = verts[(size_t)v * 3 + 1];
    vals[26] = verts[(size_t)v * 3 + 2];
    vals[27] = vnorm[(size_t)v * 3 + 0];
    vals[28] = vnorm[(size_t)v * 3 + 1];
    vals[29] = vnorm[(size_t)v * 3 + 2];

    unsigned int rec[16];
#pragma unroll
    for (int j = 0; j < 15; ++j) {
        rec[j] = f2bf(vals[2 * j]) | (f2bf(vals[2 * j + 1]) << 16);
    }
    rec[15] = 0;

    uint4* out = pk + (size_t)v * 4;
#pragma unroll
    for (int q = 0; q < 4; ++q) {
        out[q] = make_uint4(rec[q * 4 + 0], rec[q * 4 + 1], rec[q * 4 + 2], rec[q * 4 + 3]);
    }
}

template<bool PACKED>
__global__ __launch_bounds__(256) void dnmp_rk(
    const float* __restrict__ bary_coords,  // [P,4,3]
    const float* __restrict__ zbuf,         // [P,4]
    const float* __restrict__ verts,        // [V,3]
    const float* __restrict__ vfeat,        // [V,24]
    const float* __restrict__ vnorm,        // [V,3]
    const int*   __restrict__ p2f_all,      // [P,4]
    const int*   __restrict__ faces,        // [F,3]
    const int*   __restrict__ pix,          // [R]
    const uint4* __restrict__ pk,           // [V*4] packed bf16 (or null)
    float* __restrict__ out_tex,            // [R,4,24]
    float* __restrict__ out_pts,            // [R,4,3]
    float* __restrict__ out_dep,            // [R,4]
    float* __restrict__ out_nrm)            // [R,4,3]
{
    int tid = blockIdx.x * blockDim.x + threadIdx.x;
    int r = tid >> 2;
    if (r >= NRAYS) return;
    int k = tid & 3;
    int lane = threadIdx.x & 63;
    int gbase = lane & ~3;   // base lane of this ray's 4-lane group

    int p = pix[r];
    int   f = p2f_all[(size_t)p * 4 + k];
    float d = zbuf[(size_t)p * 4 + k];
    const float* bb = bary_coords + (size_t)p * 12 + k * 3;
    float w0 = bb[0], w1 = bb[1], w2 = bb[2];

    // fallback: invalid (== -1) entries take k=0's face/bary/depth
    int   f0  = __shfl(f,  gbase, 64);
    float dd0 = __shfl(d,  gbase, 64);
    float w00 = __shfl(w0, gbase, 64);
    float w01 = __shfl(w1, gbase, 64);
    float w02 = __shfl(w2, gbase, 64);
    if (f == -1) { f = f0; d = dd0; w0 = w00; w1 = w01; w2 = w02; }

    // stable argsort rank over post-fallback depths (cross-lane within group)
    int rank = 0;
#pragma unroll
    for (int j = 0; j < 4; ++j) {
        float dj = __shfl(d, gbase + j, 64);
        rank += (dj < d || (dj == d && j < k)) ? 1 : 0;
    }

    bool mask = f < 0;
    int  idx  = mask ? 0 : f;
    if (mask) { w0 = 0.f; w1 = 0.f; w2 = 0.f; }

    int i0 = faces[(size_t)idx * 3 + 0];
    int i1 = faces[(size_t)idx * 3 + 1];
    int i2 = faces[(size_t)idx * 3 + 2];

    float acc[30];
#pragma unroll
    for (int i = 0; i < 30; ++i) acc[i] = 0.f;

    const int   vi[3] = { i0, i1, i2 };
    const float ww[3] = { w0, w1, w2 };

#pragma unroll
    for (int t = 0; t < 3; ++t) {
        float w = ww[t];
        if (PACKED) {
            const uint4* row = pk + (size_t)vi[t] * 4;
            unsigned int rec[16];
#pragma unroll
            for (int q = 0; q < 4; ++q) {
                uint4 a = row[q];
                rec[q * 4 + 0] = a.x; rec[q * 4 + 1] = a.y;
                rec[q * 4 + 2] = a.z; rec[q * 4 + 3] = a.w;
            }
#pragma unroll
            for (int e = 0; e < 30; ++e) {
                unsigned int word = rec[e >> 1];
                unsigned int u = (e & 1) ? (word >> 16) : (word & 0xffffu);
                acc[e] += w * bf2f(u);
            }
        } else {
            const float4* trow = reinterpret_cast<const float4*>(vfeat + (size_t)vi[t] * DF);
#pragma unroll
            for (int q = 0; q < 6; ++q) {
                float4 a = trow[q];
                acc[q * 4 + 0] += w * a.x;
                acc[q * 4 + 1] += w * a.y;
                acc[q * 4 + 2] += w * a.z;
                acc[q * 4 + 3] += w * a.w;
            }
            const float* vv = verts + (size_t)vi[t] * 3;
            const float* nn = vnorm + (size_t)vi[t] * 3;
            acc[24] += w * vv[0]; acc[25] += w * vv[1]; acc[26] += w * vv[2];
            acc[27] += w * nn[0]; acc[28] += w * nn[1]; acc[29] += w * nn[2];
        }
    }

    int ob = r * KF + rank;
    float4* ot = reinterpret_cast<float4*>(out_tex) + (size_t)ob * 6;
#pragma unroll
    for (int q = 0; q < 6; ++q) {
        ot[q] = make_float4(acc[q * 4 + 0], acc[q * 4 + 1], acc[q * 4 + 2], acc[q * 4 + 3]);
    }
    out_pts[(size_t)ob * 3 + 0] = acc[24];
    out_pts[(size_t)ob * 3 + 1] = acc[25];
    out_pts[(size_t)ob * 3 + 2] = acc[26];
    out_nrm[(size_t)ob * 3 + 0] = acc[27];
    out_nrm[(size_t)ob * 3 + 1] = acc[28];
    out_nrm[(size_t)ob * 3 + 2] = acc[29];
    out_dep[ob] = d;
}

extern "C" void kernel_launch(void* const* d_in, const int* in_sizes, int n_in,
                              void* d_out, int out_size, void* d_ws, size_t ws_size,
                              hipStream_t stream) {
    const float* bary_coords = (const float*)d_in[0];  // [P,4,3]
    const float* zbuf        = (const float*)d_in[1];  // [P,4]
    const float* verts       = (const float*)d_in[2];  // [V,3]
    const float* vfeat       = (const float*)d_in[3];  // [V,24]
    const float* vnorm       = (const float*)d_in[4];  // [V,3]
    const int*   p2f         = (const int*)d_in[5];    // [P,4]
    const int*   faces       = (const int*)d_in[6];    // [F,3]
    const int*   pix         = (const int*)d_in[7];    // [R]

    float* out     = (float*)d_out;
    float* out_tex = out;                                   // R*4*24
    float* out_pts = out_tex + (size_t)NRAYS * KF * DF;     // R*4*3
    float* out_dep = out_pts + (size_t)NRAYS * KF * 3;      // R*4
    float* out_nrm = out_dep + (size_t)NRAYS * KF;          // R*4*3

    const size_t pk_bytes = (size_t)NVERT * 4 * sizeof(uint4);  // 26.9 MB

    dim3 block(256);
    dim3 grid_main(((size_t)NRAYS * KF + 255) / 256);

    if (ws_size >= pk_bytes) {
        uint4* pk = (uint4*)d_ws;
        dim3 grid_pack((NVERT + 255) / 256);
        pack_verts_bf16<<<grid_pack, block, 0, stream>>>(verts, vfeat, vnorm, pk);
        dnmp_rk<true><<<grid_main, block, 0, stream>>>(
            bary_coords, zbuf, verts, vfeat, vnorm, p2f, faces, pix, pk,
            out_tex, out_pts, out_dep, out_nrm);
    } else {
        dnmp_rk<false><<<grid_main, block, 0, stream>>>(
            bary_coords, zbuf, verts, vfeat, vnorm, p2f, faces, pix, nullptr,
            out_tex, out_pts, out_dep, out_nrm);
    }
}